// Round 7
// baseline (468.564 us; speedup 1.0000x reference)
//
#include <hip/hip_runtime.h>

#define N_NODES 100000
#define F 64
#define C 32
#define KH 3
#define E 1600000
#define NE (KH * E)                        // 4,800,000 edges

#define NSLICE 4                           // y col-slices; 3.2 MB < 4 MB L2/XCD
#define SLICEW 25000
#define NKEY (N_NODES * NSLICE)            // 400,000 sort keys (row*4 + slice)
#define KPB 512                            // keys per coarse bucket (= 128 rows)
#define NBUCK ((NKEY + KPB - 1) / KPB)     // 782
#define CHUNK 4096                         // edges per part1/hist block
#define EPT (CHUNK / 256)
#define NCHUNK ((NE + CHUNK - 1) / CHUNK)  // 1172
#define P2CAP 8192                         // part2 LDS capacity (mean 6144, sd 78)

// ---------------------------------------------------------------------------
// K1: y[n, c] = sum_f x[n, f] * W[f, c].  2 threads per node (16 ch each):
// 782 blocks (was 391 = 1.5 blocks/CU, parallelism-starved).
// ---------------------------------------------------------------------------
__global__ __launch_bounds__(256) void gemm_xw(const float* __restrict__ x,
                                               const float* __restrict__ W,
                                               float* __restrict__ y) {
    __shared__ float Ws[F * C];
    for (int i = threadIdx.x; i < F * C; i += 256) Ws[i] = W[i];
    __syncthreads();

    const int g = blockIdx.x * 256 + threadIdx.x;
    if (g >= N_NODES * 2) return;
    const int node = g >> 1;
    const int h = (g & 1) * 16;

    const float4* xp = (const float4*)(x + (size_t)node * F);
    float acc[16];
#pragma unroll
    for (int c = 0; c < 16; c++) acc[c] = 0.f;

#pragma unroll
    for (int i = 0; i < 16; i++) {
        float4 v = xp[i];
        const int f = i * 4;
#pragma unroll
        for (int c = 0; c < 16; c++) {
            acc[c] += v.x * Ws[(f + 0) * C + h + c];
            acc[c] += v.y * Ws[(f + 1) * C + h + c];
            acc[c] += v.z * Ws[(f + 2) * C + h + c];
            acc[c] += v.w * Ws[(f + 3) * C + h + c];
        }
    }

    float4* yo = (float4*)(y + (size_t)node * C + h);
#pragma unroll
    for (int i = 0; i < 4; i++)
        yo[i] = make_float4(acc[4 * i], acc[4 * i + 1], acc[4 * i + 2], acc[4 * i + 3]);
}

// ---------------------------------------------------------------------------
// K2: coarse histogram — LDS-aggregated. bucket = row >> 7.
// ---------------------------------------------------------------------------
__global__ __launch_bounds__(256) void hist_c(const int* __restrict__ rows,
                                              int* __restrict__ hcnt) {
    __shared__ int hh[NBUCK];
    for (int i = threadIdx.x; i < NBUCK; i += 256) hh[i] = 0;
    __syncthreads();
    const int base = blockIdx.x * CHUNK;
#pragma unroll
    for (int j = 0; j < EPT; j++) {
        const int e = base + j * 256 + threadIdx.x;
        if (e < NE) atomicAdd(&hh[rows[e] >> 7], 1);
    }
    __syncthreads();
    for (int i = threadIdx.x; i < NBUCK; i += 256) {
        const int cc = hh[i];
        if (cc) atomicAdd(&hcnt[i], cc);
    }
}

// ---------------------------------------------------------------------------
// K3: single-block scan of 782 bucket counts -> bstart, bcur, rs sentinel.
// ---------------------------------------------------------------------------
__global__ __launch_bounds__(256) void scan_c(const int* __restrict__ hcnt,
                                              int* __restrict__ bstart,
                                              int* __restrict__ bcur,
                                              int* __restrict__ rs_start) {
    __shared__ int sA[1024], sB[1024];
    const int tid = threadIdx.x;
    for (int i = tid; i < 1024; i += 256) sA[i] = (i < NBUCK) ? hcnt[i] : 0;
    __syncthreads();
    int* src = sA;
    int* dst = sB;
    for (int d = 1; d < 1024; d <<= 1) {
        for (int i = tid; i < 1024; i += 256) {
            int v = src[i];
            if (i >= d) v += src[i - d];
            dst[i] = v;
        }
        __syncthreads();
        int* t = src; src = dst; dst = t;
    }
    for (int i = tid; i < NBUCK; i += 256) {
        const int excl = (i == 0) ? 0 : src[i - 1];
        bstart[i] = excl;
        bcur[i] = excl;
    }
    if (tid == 0) {
        bstart[NBUCK] = NE;
        rs_start[NKEY] = NE;
    }
}

// ---------------------------------------------------------------------------
// K4: part1 — LDS-staged coarse partition. Scan replaced by thread-serial(4)
// + wave-shuffle scan: 10 barriers -> 2, ~80 LDS scan-ops -> 8.
// ---------------------------------------------------------------------------
__global__ __launch_bounds__(256) void part1_k(const float* __restrict__ vals,
                                               const int* __restrict__ rows,
                                               const int* __restrict__ cols,
                                               const float* __restrict__ alpha,
                                               int* __restrict__ bcur,
                                               int2* __restrict__ edgebuf) {
    __shared__ int sA[1024];                 // raw counts
    __shared__ int sS[1024];                 // inclusive scan
    __shared__ int wtot[4];
    __shared__ int lpos[NBUCK];
    __shared__ int lbase[NBUCK];
    __shared__ int2 stage[CHUNK];            // 32 KB
    __shared__ unsigned short sbin[CHUNK];   // 8 KB

    const int tid = threadIdx.x;
    const int base = blockIdx.x * CHUNK;

    for (int i = tid; i < 1024; i += 256) sA[i] = 0;
    __syncthreads();

    int kj[EPT], cj[EPT];
    float wj[EPT];
#pragma unroll
    for (int j = 0; j < EPT; j++) {
        const int e = base + j * 256 + tid;
        if (e < NE) {
            const int r = rows[e];
            cj[j] = cols[e];
            kj[j] = r * NSLICE + cj[j] / SLICEW;
            const int k = (e >= 2 * E) ? 2 : (e >= E) ? 1 : 0;
            wj[j] = vals[e] * alpha[k];
            atomicAdd(&sA[kj[j] >> 9], 1);
        } else {
            kj[j] = -1;
        }
    }
    __syncthreads();

    {   // wave-scan: thread handles 4 consecutive bins
        const int lane = tid & 63;
        const int w = tid >> 6;
        const int b4 = tid * 4;
        const int a0 = sA[b4], a1 = sA[b4 + 1], a2 = sA[b4 + 2], a3 = sA[b4 + 3];
        const int l1 = a0 + a1, l2 = l1 + a2, l3 = l2 + a3;
        int sc = l3;
#pragma unroll
        for (int d = 1; d < 64; d <<= 1) {
            int u = __shfl_up(sc, d);
            if (lane >= d) sc += u;
        }
        if (lane == 63) wtot[w] = sc;
        __syncthreads();
        int wb = 0;
#pragma unroll
        for (int q = 0; q < 4; q++)
            if (q < w) wb += wtot[q];
        const int tb = wb + sc - l3;
        sS[b4] = tb + a0; sS[b4 + 1] = tb + l1; sS[b4 + 2] = tb + l2; sS[b4 + 3] = tb + l3;
    }
    __syncthreads();

    for (int i = tid; i < NBUCK; i += 256) {
        const int excl = (i == 0) ? 0 : sS[i - 1];
        const int cnt = sS[i] - excl;
        lpos[i] = excl;
        if (cnt) lbase[i] = atomicAdd(&bcur[i], cnt);
    }
    __syncthreads();

#pragma unroll
    for (int j = 0; j < EPT; j++) {
        if (kj[j] >= 0) {
            const int b = kj[j] >> 9;
            const int p = atomicAdd(&lpos[b], 1);
            stage[p] = make_int2(((kj[j] & (KPB - 1)) << 17) | cj[j],
                                 __float_as_int(wj[j]));
            sbin[p] = (unsigned short)b;
        }
    }
    __syncthreads();

    const int total = sS[1023];
    for (int p = tid; p < total; p += 256) {
        const int b = sbin[p];
        const int excl = (b == 0) ? 0 : sS[b - 1];
        edgebuf[lbase[b] + (p - excl)] = stage[p];
    }
}

// ---------------------------------------------------------------------------
// K5: part2 — per-bucket in-LDS counting sort (wave-scan over 512 sub-keys).
// ---------------------------------------------------------------------------
__global__ __launch_bounds__(256) void part2_k(const int* __restrict__ bstart,
                                               int* __restrict__ rs_start,
                                               int2* __restrict__ edgebuf) {
    __shared__ int2 sstage[P2CAP];   // 64 KB
    __shared__ int sh[KPB];          // counts
    __shared__ int sg[KPB];          // inclusive scan
    __shared__ int wtot[4];
    __shared__ int lbin[KPB];        // write cursors

    const int tid = threadIdx.x;
    const int b = blockIdx.x;
    const int bs = bstart[b];
    const int be = bstart[b + 1];
    const int n = be - bs;

    for (int k = tid; k < KPB; k += 256) sh[k] = 0;
    __syncthreads();

    if (n <= P2CAP) {
        for (int i = tid; i < n; i += 256) {
            const int2 e = edgebuf[bs + i];
            sstage[i] = e;
            atomicAdd(&sh[((unsigned)e.x) >> 17], 1);
        }
    }
    __syncthreads();

    {   // wave-scan: thread handles 2 consecutive sub-keys
        const int lane = tid & 63;
        const int w = tid >> 6;
        const int a0 = sh[2 * tid], a1 = sh[2 * tid + 1];
        const int l1 = a0 + a1;
        int sc = l1;
#pragma unroll
        for (int d = 1; d < 64; d <<= 1) {
            int u = __shfl_up(sc, d);
            if (lane >= d) sc += u;
        }
        if (lane == 63) wtot[w] = sc;
        __syncthreads();
        int wb = 0;
#pragma unroll
        for (int q = 0; q < 4; q++)
            if (q < w) wb += wtot[q];
        const int tb = wb + sc - l1;
        sg[2 * tid] = tb + a0; sg[2 * tid + 1] = tb + l1;
    }
    __syncthreads();

    for (int k = tid; k < KPB; k += 256) {
        const int st = bs + ((k == 0) ? 0 : sg[k - 1]);
        lbin[k] = st;
        const int idx = (b << 9) + k;
        if (idx < NKEY) rs_start[idx] = st;
    }
    __syncthreads();

    if (n > P2CAP) return;  // 26-sigma impossible

    for (int i = tid; i < n; i += 256) {
        const int2 e = sstage[i];
        const int sub = ((unsigned)e.x) >> 17;
        const int pos = atomicAdd(&lbin[sub], 1);
        edgebuf[pos] = e;
    }
}

// ---------------------------------------------------------------------------
// K6: gather — ONE WAVE per (row, slice) task. Lanes: p = lane>>5 (edge
// parity), c = lane&31 (channel). 8 edges/iter = 4 y-lines in flight, no
// intra-wave n-divergence. s = blk&3 keeps each XCD on one 3.2 MB y-slice.
// atomic_mode==0: plain nontemporal store to per-slice partial (no atomics,
// no out memset). atomic_mode==1: round-6 behavior (atomic merge + bias@s0).
// ---------------------------------------------------------------------------
__global__ __launch_bounds__(256) void gatherw_k(const long long* __restrict__ eb,
                                                 const int* __restrict__ rs_start,
                                                 const float* __restrict__ y,
                                                 const float* __restrict__ bias,
                                                 float* __restrict__ out,
                                                 float* __restrict__ parts,
                                                 const int atomic_mode) {
    const int wid = threadIdx.x >> 6;   // 4 waves/block = 4 rows, same slice
    const int lane = threadIdx.x & 63;
    const int p = lane >> 5;
    const int c = lane & 31;
    const int s = blockIdx.x & (NSLICE - 1);
    const int row = (blockIdx.x >> 2) * 4 + wid;
    const int key = row * NSLICE + s;
    const int st = rs_start[key];
    const int en = rs_start[key + 1];

    float acc = 0.f;
    int i = st;
    for (; i + 8 <= en; i += 8) {
        const long long la = __builtin_nontemporal_load(&eb[i + p]);
        const long long lb = __builtin_nontemporal_load(&eb[i + 2 + p]);
        const long long lc = __builtin_nontemporal_load(&eb[i + 4 + p]);
        const long long ld = __builtin_nontemporal_load(&eb[i + 6 + p]);
        const float ya = y[(((int)la) & 0x1FFFF) * C + c];
        const float yb = y[(((int)lb) & 0x1FFFF) * C + c];
        const float yc = y[(((int)lc) & 0x1FFFF) * C + c];
        const float yd = y[(((int)ld) & 0x1FFFF) * C + c];
        acc += __int_as_float((int)(la >> 32)) * ya;
        acc += __int_as_float((int)(lb >> 32)) * yb;
        acc += __int_as_float((int)(lc >> 32)) * yc;
        acc += __int_as_float((int)(ld >> 32)) * yd;
    }
    if (i + 4 <= en) {
        const long long la = __builtin_nontemporal_load(&eb[i + p]);
        const long long lb = __builtin_nontemporal_load(&eb[i + 2 + p]);
        acc += __int_as_float((int)(la >> 32)) * y[(((int)la) & 0x1FFFF) * C + c];
        acc += __int_as_float((int)(lb >> 32)) * y[(((int)lb) & 0x1FFFF) * C + c];
        i += 4;
    }
    if (i + 2 <= en) {
        const long long la = __builtin_nontemporal_load(&eb[i + p]);
        acc += __int_as_float((int)(la >> 32)) * y[(((int)la) & 0x1FFFF) * C + c];
        i += 2;
    }
    if (i < en && p == 0) {
        const long long la = __builtin_nontemporal_load(&eb[i]);
        acc += __int_as_float((int)(la >> 32)) * y[(((int)la) & 0x1FFFF) * C + c];
    }

    acc += __shfl_down(acc, 32);  // combine p=1 half into p=0 half

    if (p == 0) {
        if (atomic_mode) {
            if (s == 0) acc += bias[c];
            unsafeAtomicAdd(out + (size_t)row * C + c, acc);
        } else {
            float* tgt = (s == 0) ? out : parts + (size_t)(s - 1) * (N_NODES * C);
            __builtin_nontemporal_store(acc, tgt + (size_t)row * C + c);
        }
    }
}

// ---------------------------------------------------------------------------
// K7: reduce (plain-store path): out = out + p1 + p2 + p3 + bias
// ---------------------------------------------------------------------------
__global__ __launch_bounds__(256) void reduce4_k(float* __restrict__ out,
                                                 const float* __restrict__ parts,
                                                 const float* __restrict__ bias) {
    const int idx = (blockIdx.x * 256 + threadIdx.x) * 4;
    if (idx >= N_NODES * C) return;
    const int c0 = idx & (C - 1);
    float4 v = *(float4*)(out + idx);
    const float4 a = *(const float4*)(parts + idx);
    const float4 b2 = *(const float4*)(parts + (size_t)N_NODES * C + idx);
    const float4 c2 = *(const float4*)(parts + (size_t)2 * N_NODES * C + idx);
    const float4 bv = *(const float4*)(bias + c0);
    v.x += a.x + b2.x + c2.x + bv.x;
    v.y += a.y + b2.y + c2.y + bv.y;
    v.z += a.z + b2.z + c2.z + bv.z;
    v.w += a.w + b2.w + c2.w + bv.w;
    *(float4*)(out + idx) = v;
}

// ---------------------------------------------------------------------------
// Fallback (proven): atomic scatter if workspace too small even for mid path.
// ---------------------------------------------------------------------------
__global__ __launch_bounds__(256) void scatter_edges(
    const float* __restrict__ vals, const int* __restrict__ rows,
    const int* __restrict__ cols, const float* __restrict__ alpha,
    const float* __restrict__ y, float* __restrict__ out_acc) {
    const int t = blockIdx.x * 256 + threadIdx.x;
    const int e = t >> 5;
    const int c = t & 31;
    if (e >= KH * E) return;
    const int k = (e >= 2 * E) ? 2 : (e >= E) ? 1 : 0;
    const float w = vals[e] * alpha[k];
    const float yv = y[(size_t)cols[e] * C + c];
    unsafeAtomicAdd(out_acc + (size_t)rows[e] * C + c, w * yv);
}

__global__ __launch_bounds__(256) void finalize_k(float* __restrict__ out,
                                                  const float* __restrict__ bias) {
    const int idx = (blockIdx.x * 256 + threadIdx.x) * 4;
    if (idx >= N_NODES * C) return;
    const int c0 = idx & (C - 1);
    float4 v = *(float4*)(out + idx);
    v.x += bias[c0 + 0];
    v.y += bias[c0 + 1];
    v.z += bias[c0 + 2];
    v.w += bias[c0 + 3];
    *(float4*)(out + idx) = v;
}

// ---------------------------------------------------------------------------
extern "C" void kernel_launch(void* const* d_in, const int* in_sizes, int n_in,
                              void* d_out, int out_size, void* d_ws, size_t ws_size,
                              hipStream_t stream) {
    const float* x         = (const float*)d_in[0];
    const float* edge_vals = (const float*)d_in[1];
    const float* W         = (const float*)d_in[2];
    const float* b         = (const float*)d_in[3];
    const float* alpha     = (const float*)d_in[4];
    const int*   edge_rows = (const int*)d_in[5];
    const int*   edge_cols = (const int*)d_in[6];
    float*       out       = (float*)d_out;

    // Workspace layout
    const size_t offY   = 0;                                   // 12,800,000
    const size_t offEB  = (size_t)N_NODES * C * 4;             // +38,400,000
    const size_t offRS  = offEB + (size_t)NE * 8;              // 51,200,000
    const size_t offBS  = offRS + (((size_t)(NKEY + 1) * 4 + 255) & ~(size_t)255);
    const size_t offBC  = offBS + (((NBUCK + 1) * 4 + 255) & ~(size_t)255);
    const size_t offHC  = offBC + ((NBUCK * 4 + 255) & ~(size_t)255);
    const size_t offP   = offHC + ((NBUCK * 4 + 255) & ~(size_t)255);
    const size_t need_mid = offP;                              // ~52.81 MB (proven fits)
    const size_t need_big = offP + (size_t)3 * N_NODES * C * 4; // ~91.2 MB

    float* y = (float*)((char*)d_ws + offY);

    gemm_xw<<<(N_NODES * 2 + 255) / 256, 256, 0, stream>>>(x, W, y);

    if (ws_size >= need_mid) {
        int2* edgebuf  = (int2*)((char*)d_ws + offEB);
        int*  rs_start = (int*)((char*)d_ws + offRS);
        int*  bstart   = (int*)((char*)d_ws + offBS);
        int*  bcur     = (int*)((char*)d_ws + offBC);
        int*  hcnt     = (int*)((char*)d_ws + offHC);
        float* parts   = (float*)((char*)d_ws + offP);
        const int big  = (ws_size >= need_big) ? 1 : 0;

        hipMemsetAsync(hcnt, 0, (size_t)NBUCK * 4, stream);
        if (!big)
            hipMemsetAsync(out, 0, (size_t)N_NODES * C * sizeof(float), stream);

        hist_c<<<NCHUNK, 256, 0, stream>>>(edge_rows, hcnt);
        scan_c<<<1, 256, 0, stream>>>(hcnt, bstart, bcur, rs_start);
        part1_k<<<NCHUNK, 256, 0, stream>>>(edge_vals, edge_rows, edge_cols,
                                            alpha, bcur, edgebuf);
        part2_k<<<NBUCK, 256, 0, stream>>>(bstart, rs_start, edgebuf);
        gatherw_k<<<(N_NODES / 4) * NSLICE, 256, 0, stream>>>(
            (const long long*)edgebuf, rs_start, y, b, out, parts, big ? 0 : 1);
        if (big)
            reduce4_k<<<(N_NODES * C / 4 + 255) / 256, 256, 0, stream>>>(out, parts, b);
    } else {
        hipMemsetAsync(out, 0, (size_t)N_NODES * C * sizeof(float), stream);
        const long long scatter_threads = (long long)KH * E * C;
        const int scatter_blocks = (int)((scatter_threads + 255) / 256);
        scatter_edges<<<scatter_blocks, 256, 0, stream>>>(
            edge_vals, edge_rows, edge_cols, alpha, y, out);
        finalize_k<<<(N_NODES * C / 4 + 255) / 256, 256, 0, stream>>>(out, b);
    }
}

// Round 10
// 407.670 us; speedup vs baseline: 1.1494x; 1.1494x over previous
//
#include <hip/hip_runtime.h>

#define N_NODES 100000
#define F 64
#define C 32
#define KH 3
#define E 1600000
#define NE (KH * E)                        // 4,800,000 edges

#define NSLICE 4                           // y col-slices; 3.2 MB < 4 MB L2/XCD
#define SLICEW 25000
#define NKEY (N_NODES * NSLICE)            // 400,000 sort keys (row*4 + slice)
#define KPB 512                            // keys per coarse bucket (= 128 rows)
#define NBUCK ((NKEY + KPB - 1) / KPB)     // 782
#define CHUNK 4096                         // edges per part1/hist block
#define EPT (CHUNK / 256)
#define NCHUNK ((NE + CHUNK - 1) / CHUNK)  // 1172
#define P2CAP 8192                         // part2 LDS capacity (mean 6144, sd 78)

// ---------------------------------------------------------------------------
// K1: y[n, c] = sum_f x[n, f] * W[f, c].  2 threads per node (16 ch each).
// ---------------------------------------------------------------------------
__global__ __launch_bounds__(256) void gemm_xw(const float* __restrict__ x,
                                               const float* __restrict__ W,
                                               float* __restrict__ y) {
    __shared__ float Ws[F * C];
    for (int i = threadIdx.x; i < F * C; i += 256) Ws[i] = W[i];
    __syncthreads();

    const int g = blockIdx.x * 256 + threadIdx.x;
    if (g >= N_NODES * 2) return;
    const int node = g >> 1;
    const int h = (g & 1) * 16;

    const float4* xp = (const float4*)(x + (size_t)node * F);
    float acc[16];
#pragma unroll
    for (int c = 0; c < 16; c++) acc[c] = 0.f;

#pragma unroll
    for (int i = 0; i < 16; i++) {
        float4 v = xp[i];
        const int f = i * 4;
#pragma unroll
        for (int c = 0; c < 16; c++) {
            acc[c] += v.x * Ws[(f + 0) * C + h + c];
            acc[c] += v.y * Ws[(f + 1) * C + h + c];
            acc[c] += v.z * Ws[(f + 2) * C + h + c];
            acc[c] += v.w * Ws[(f + 3) * C + h + c];
        }
    }

    float4* yo = (float4*)(y + (size_t)node * C + h);
#pragma unroll
    for (int i = 0; i < 4; i++)
        yo[i] = make_float4(acc[4 * i], acc[4 * i + 1], acc[4 * i + 2], acc[4 * i + 3]);
}

// ---------------------------------------------------------------------------
// K2: coarse histogram — LDS-aggregated. bucket = row >> 7.
// ---------------------------------------------------------------------------
__global__ __launch_bounds__(256) void hist_c(const int* __restrict__ rows,
                                              int* __restrict__ hcnt) {
    __shared__ int hh[NBUCK];
    for (int i = threadIdx.x; i < NBUCK; i += 256) hh[i] = 0;
    __syncthreads();
    const int base = blockIdx.x * CHUNK;
#pragma unroll
    for (int j = 0; j < EPT; j++) {
        const int e = base + j * 256 + threadIdx.x;
        if (e < NE) atomicAdd(&hh[rows[e] >> 7], 1);
    }
    __syncthreads();
    for (int i = threadIdx.x; i < NBUCK; i += 256) {
        const int cc = hh[i];
        if (cc) atomicAdd(&hcnt[i], cc);
    }
}

// ---------------------------------------------------------------------------
// K3: single-block scan of 782 bucket counts -> bstart, bcur, rs sentinel.
// ---------------------------------------------------------------------------
__global__ __launch_bounds__(256) void scan_c(const int* __restrict__ hcnt,
                                              int* __restrict__ bstart,
                                              int* __restrict__ bcur,
                                              int* __restrict__ rs_start) {
    __shared__ int sA[1024], sB[1024];
    const int tid = threadIdx.x;
    for (int i = tid; i < 1024; i += 256) sA[i] = (i < NBUCK) ? hcnt[i] : 0;
    __syncthreads();
    int* src = sA;
    int* dst = sB;
    for (int d = 1; d < 1024; d <<= 1) {
        for (int i = tid; i < 1024; i += 256) {
            int v = src[i];
            if (i >= d) v += src[i - d];
            dst[i] = v;
        }
        __syncthreads();
        int* t = src; src = dst; dst = t;
    }
    for (int i = tid; i < NBUCK; i += 256) {
        const int excl = (i == 0) ? 0 : src[i - 1];
        bstart[i] = excl;
        bcur[i] = excl;
    }
    if (tid == 0) {
        bstart[NBUCK] = NE;
        rs_start[NKEY] = NE;
    }
}

// ---------------------------------------------------------------------------
// K4: part1 — LDS-staged coarse partition (wave-shuffle scan, 2 barriers).
// bucket = row>>7. Entry: { (key&511)<<17 | col , val*alpha }.
// ---------------------------------------------------------------------------
__global__ __launch_bounds__(256) void part1_k(const float* __restrict__ vals,
                                               const int* __restrict__ rows,
                                               const int* __restrict__ cols,
                                               const float* __restrict__ alpha,
                                               int* __restrict__ bcur,
                                               int2* __restrict__ edgebuf) {
    __shared__ int sA[1024];                 // raw counts
    __shared__ int sS[1024];                 // inclusive scan
    __shared__ int wtot[4];
    __shared__ int lpos[NBUCK];
    __shared__ int lbase[NBUCK];
    __shared__ int2 stage[CHUNK];            // 32 KB
    __shared__ unsigned short sbin[CHUNK];   // 8 KB

    const int tid = threadIdx.x;
    const int base = blockIdx.x * CHUNK;

    for (int i = tid; i < 1024; i += 256) sA[i] = 0;
    __syncthreads();

    int kj[EPT], cj[EPT];
    float wj[EPT];
#pragma unroll
    for (int j = 0; j < EPT; j++) {
        const int e = base + j * 256 + tid;
        if (e < NE) {
            const int r = rows[e];
            cj[j] = cols[e];
            kj[j] = r * NSLICE + cj[j] / SLICEW;
            const int k = (e >= 2 * E) ? 2 : (e >= E) ? 1 : 0;
            wj[j] = vals[e] * alpha[k];
            atomicAdd(&sA[kj[j] >> 9], 1);
        } else {
            kj[j] = -1;
        }
    }
    __syncthreads();

    {   // wave-scan: thread handles 4 consecutive bins
        const int lane = tid & 63;
        const int w = tid >> 6;
        const int b4 = tid * 4;
        const int a0 = sA[b4], a1 = sA[b4 + 1], a2 = sA[b4 + 2], a3 = sA[b4 + 3];
        const int l1 = a0 + a1, l2 = l1 + a2, l3 = l2 + a3;
        int sc = l3;
#pragma unroll
        for (int d = 1; d < 64; d <<= 1) {
            int u = __shfl_up(sc, d);
            if (lane >= d) sc += u;
        }
        if (lane == 63) wtot[w] = sc;
        __syncthreads();
        int wb = 0;
#pragma unroll
        for (int q = 0; q < 4; q++)
            if (q < w) wb += wtot[q];
        const int tb = wb + sc - l3;
        sS[b4] = tb + a0; sS[b4 + 1] = tb + l1; sS[b4 + 2] = tb + l2; sS[b4 + 3] = tb + l3;
    }
    __syncthreads();

    for (int i = tid; i < NBUCK; i += 256) {
        const int excl = (i == 0) ? 0 : sS[i - 1];
        const int cnt = sS[i] - excl;
        lpos[i] = excl;
        if (cnt) lbase[i] = atomicAdd(&bcur[i], cnt);
    }
    __syncthreads();

#pragma unroll
    for (int j = 0; j < EPT; j++) {
        if (kj[j] >= 0) {
            const int b = kj[j] >> 9;
            const int p = atomicAdd(&lpos[b], 1);
            stage[p] = make_int2(((kj[j] & (KPB - 1)) << 17) | cj[j],
                                 __float_as_int(wj[j]));
            sbin[p] = (unsigned short)b;
        }
    }
    __syncthreads();

    const int total = sS[1023];
    for (int p = tid; p < total; p += 256) {
        const int b = sbin[p];
        const int excl = (b == 0) ? 0 : sS[b - 1];
        edgebuf[lbase[b] + (p - excl)] = stage[p];
    }
}

// ---------------------------------------------------------------------------
// K5: part2 — per-bucket in-LDS counting sort (wave-scan over 512 sub-keys).
// ---------------------------------------------------------------------------
__global__ __launch_bounds__(256) void part2_k(const int* __restrict__ bstart,
                                               int* __restrict__ rs_start,
                                               int2* __restrict__ edgebuf) {
    __shared__ int2 sstage[P2CAP];   // 64 KB
    __shared__ int sh[KPB];          // counts
    __shared__ int sg[KPB];          // inclusive scan
    __shared__ int wtot[4];
    __shared__ int lbin[KPB];        // write cursors

    const int tid = threadIdx.x;
    const int b = blockIdx.x;
    const int bs = bstart[b];
    const int be = bstart[b + 1];
    const int n = be - bs;

    for (int k = tid; k < KPB; k += 256) sh[k] = 0;
    __syncthreads();

    if (n <= P2CAP) {
        for (int i = tid; i < n; i += 256) {
            const int2 e = edgebuf[bs + i];
            sstage[i] = e;
            atomicAdd(&sh[((unsigned)e.x) >> 17], 1);
        }
    }
    __syncthreads();

    {   // wave-scan: thread handles 2 consecutive sub-keys
        const int lane = tid & 63;
        const int w = tid >> 6;
        const int a0 = sh[2 * tid], a1 = sh[2 * tid + 1];
        const int l1 = a0 + a1;
        int sc = l1;
#pragma unroll
        for (int d = 1; d < 64; d <<= 1) {
            int u = __shfl_up(sc, d);
            if (lane >= d) sc += u;
        }
        if (lane == 63) wtot[w] = sc;
        __syncthreads();
        int wb = 0;
#pragma unroll
        for (int q = 0; q < 4; q++)
            if (q < w) wb += wtot[q];
        const int tb = wb + sc - l1;
        sg[2 * tid] = tb + a0; sg[2 * tid + 1] = tb + l1;
    }
    __syncthreads();

    for (int k = tid; k < KPB; k += 256) {
        const int st = bs + ((k == 0) ? 0 : sg[k - 1]);
        lbin[k] = st;
        const int idx = (b << 9) + k;
        if (idx < NKEY) rs_start[idx] = st;
    }
    __syncthreads();

    if (n > P2CAP) return;  // 26-sigma impossible

    for (int i = tid; i < n; i += 256) {
        const int2 e = sstage[i];
        const int sub = ((unsigned)e.x) >> 17;
        const int pos = atomicAdd(&lbin[sub], 1);
        edgebuf[pos] = e;
    }
}

// ---------------------------------------------------------------------------
// K6: gather — half-wave (32 lanes = channels) per (row, slice) task, 8 tasks
// per block. r6's PROVEN branch structure, deepened: 8-deep first tier (16
// loads in flight), then 4-deep, then scalar tail. Typical n=12 task: 2
// dependent rounds (was 3). s = blk&3 keeps each XCD on one L2 y-slice.
// ---------------------------------------------------------------------------
__global__ __launch_bounds__(256) void gathers9_k(const long long* __restrict__ eb,
                                                  const int* __restrict__ rs_start,
                                                  const float* __restrict__ y,
                                                  const float* __restrict__ bias,
                                                  float* __restrict__ out) {
    const int blk = blockIdx.x;
    const int s = blk & (NSLICE - 1);
    const int row = (blk >> 2) * 8 + (threadIdx.x >> 5);
    const int c = threadIdx.x & 31;
    const int key = row * NSLICE + s;
    const int st = rs_start[key];
    const int en = rs_start[key + 1];

    float acc = (s == 0) ? bias[c] : 0.f;

    int i = st;
    for (; i + 8 <= en; i += 8) {  // 8 edges: 16 loads in flight
        const long long l0 = __builtin_nontemporal_load(&eb[i + 0]);
        const long long l1 = __builtin_nontemporal_load(&eb[i + 1]);
        const long long l2 = __builtin_nontemporal_load(&eb[i + 2]);
        const long long l3 = __builtin_nontemporal_load(&eb[i + 3]);
        const long long l4 = __builtin_nontemporal_load(&eb[i + 4]);
        const long long l5 = __builtin_nontemporal_load(&eb[i + 5]);
        const long long l6 = __builtin_nontemporal_load(&eb[i + 6]);
        const long long l7 = __builtin_nontemporal_load(&eb[i + 7]);
        const float y0 = y[(((int)l0) & 0x1FFFF) * C + c];
        const float y1 = y[(((int)l1) & 0x1FFFF) * C + c];
        const float y2 = y[(((int)l2) & 0x1FFFF) * C + c];
        const float y3 = y[(((int)l3) & 0x1FFFF) * C + c];
        const float y4 = y[(((int)l4) & 0x1FFFF) * C + c];
        const float y5 = y[(((int)l5) & 0x1FFFF) * C + c];
        const float y6 = y[(((int)l6) & 0x1FFFF) * C + c];
        const float y7 = y[(((int)l7) & 0x1FFFF) * C + c];
        acc += __int_as_float((int)(l0 >> 32)) * y0;
        acc += __int_as_float((int)(l1 >> 32)) * y1;
        acc += __int_as_float((int)(l2 >> 32)) * y2;
        acc += __int_as_float((int)(l3 >> 32)) * y3;
        acc += __int_as_float((int)(l4 >> 32)) * y4;
        acc += __int_as_float((int)(l5 >> 32)) * y5;
        acc += __int_as_float((int)(l6 >> 32)) * y6;
        acc += __int_as_float((int)(l7 >> 32)) * y7;
    }
    for (; i + 4 <= en; i += 4) {  // r6's proven 4-deep tier
        const long long l0 = __builtin_nontemporal_load(&eb[i + 0]);
        const long long l1 = __builtin_nontemporal_load(&eb[i + 1]);
        const long long l2 = __builtin_nontemporal_load(&eb[i + 2]);
        const long long l3 = __builtin_nontemporal_load(&eb[i + 3]);
        const float y0 = y[(((int)l0) & 0x1FFFF) * C + c];
        const float y1 = y[(((int)l1) & 0x1FFFF) * C + c];
        const float y2 = y[(((int)l2) & 0x1FFFF) * C + c];
        const float y3 = y[(((int)l3) & 0x1FFFF) * C + c];
        acc += __int_as_float((int)(l0 >> 32)) * y0;
        acc += __int_as_float((int)(l1 >> 32)) * y1;
        acc += __int_as_float((int)(l2 >> 32)) * y2;
        acc += __int_as_float((int)(l3 >> 32)) * y3;
    }
    for (; i < en; i++) {
        const long long l0 = __builtin_nontemporal_load(&eb[i]);
        acc += __int_as_float((int)(l0 >> 32)) * y[(((int)l0) & 0x1FFFF) * C + c];
    }

    unsafeAtomicAdd(out + (size_t)row * C + c, acc);
}

// ---------------------------------------------------------------------------
// Fallback (proven): atomic scatter if workspace too small.
// ---------------------------------------------------------------------------
__global__ __launch_bounds__(256) void scatter_edges(
    const float* __restrict__ vals, const int* __restrict__ rows,
    const int* __restrict__ cols, const float* __restrict__ alpha,
    const float* __restrict__ y, float* __restrict__ out_acc) {
    const int t = blockIdx.x * 256 + threadIdx.x;
    const int e = t >> 5;
    const int c = t & 31;
    if (e >= KH * E) return;
    const int k = (e >= 2 * E) ? 2 : (e >= E) ? 1 : 0;
    const float w = vals[e] * alpha[k];
    const float yv = y[(size_t)cols[e] * C + c];
    unsafeAtomicAdd(out_acc + (size_t)rows[e] * C + c, w * yv);
}

__global__ __launch_bounds__(256) void finalize_k(float* __restrict__ out,
                                                  const float* __restrict__ bias) {
    const int idx = (blockIdx.x * 256 + threadIdx.x) * 4;
    if (idx >= N_NODES * C) return;
    const int c0 = idx & (C - 1);
    float4 v = *(float4*)(out + idx);
    v.x += bias[c0 + 0];
    v.y += bias[c0 + 1];
    v.z += bias[c0 + 2];
    v.w += bias[c0 + 3];
    *(float4*)(out + idx) = v;
}

// ---------------------------------------------------------------------------
extern "C" void kernel_launch(void* const* d_in, const int* in_sizes, int n_in,
                              void* d_out, int out_size, void* d_ws, size_t ws_size,
                              hipStream_t stream) {
    const float* x         = (const float*)d_in[0];
    const float* edge_vals = (const float*)d_in[1];
    const float* W         = (const float*)d_in[2];
    const float* b         = (const float*)d_in[3];
    const float* alpha     = (const float*)d_in[4];
    const int*   edge_rows = (const int*)d_in[5];
    const int*   edge_cols = (const int*)d_in[6];
    float*       out       = (float*)d_out;

    // Workspace layout (proven to fit: ~52.81 MB)
    const size_t offY   = 0;                                   // 12,800,000
    const size_t offEB  = (size_t)N_NODES * C * 4;             // +38,400,000
    const size_t offRS  = offEB + (size_t)NE * 8;              // 51,200,000
    const size_t offBS  = offRS + (((size_t)(NKEY + 1) * 4 + 255) & ~(size_t)255);
    const size_t offBC  = offBS + (((NBUCK + 1) * 4 + 255) & ~(size_t)255);
    const size_t offHC  = offBC + ((NBUCK * 4 + 255) & ~(size_t)255);
    const size_t need   = offHC + (size_t)NBUCK * 4;

    float* y = (float*)((char*)d_ws + offY);

    gemm_xw<<<(N_NODES * 2 + 255) / 256, 256, 0, stream>>>(x, W, y);

    if (ws_size >= need) {
        int2* edgebuf  = (int2*)((char*)d_ws + offEB);
        int*  rs_start = (int*)((char*)d_ws + offRS);
        int*  bstart   = (int*)((char*)d_ws + offBS);
        int*  bcur     = (int*)((char*)d_ws + offBC);
        int*  hcnt     = (int*)((char*)d_ws + offHC);

        hipMemsetAsync(hcnt, 0, (size_t)NBUCK * 4, stream);
        hipMemsetAsync(out, 0, (size_t)N_NODES * C * sizeof(float), stream);

        hist_c<<<NCHUNK, 256, 0, stream>>>(edge_rows, hcnt);
        scan_c<<<1, 256, 0, stream>>>(hcnt, bstart, bcur, rs_start);
        part1_k<<<NCHUNK, 256, 0, stream>>>(edge_vals, edge_rows, edge_cols,
                                            alpha, bcur, edgebuf);
        part2_k<<<NBUCK, 256, 0, stream>>>(bstart, rs_start, edgebuf);
        gathers9_k<<<(N_NODES / 8) * NSLICE, 256, 0, stream>>>(
            (const long long*)edgebuf, rs_start, y, b, out);
    } else {
        hipMemsetAsync(out, 0, (size_t)N_NODES * C * sizeof(float), stream);
        const long long scatter_threads = (long long)KH * E * C;
        const int scatter_blocks = (int)((scatter_threads + 255) / 256);
        scatter_edges<<<scatter_blocks, 256, 0, stream>>>(
            edge_vals, edge_rows, edge_cols, alpha, y, out);
        finalize_k<<<(N_NODES * C / 4 + 255) / 256, 256, 0, stream>>>(out, b);
    }
}

// Round 11
// 378.633 us; speedup vs baseline: 1.2375x; 1.0767x over previous
//
#include <hip/hip_runtime.h>

#define N_NODES 100000
#define F 64
#define C 32
#define KH 3
#define E 1600000
#define NE (KH * E)                        // 4,800,000 edges

#define NSLICE 4                           // y col-slices; 3.2 MB < 4 MB L2/XCD
#define SLICEW 25000
#define NKEY (N_NODES * NSLICE)            // 400,000 sort keys (row*4 + slice)
#define KPB 512                            // keys per coarse bucket (= 128 rows)
#define NBUCK ((NKEY + KPB - 1) / KPB)     // 782
#define CHUNK 4096                         // edges per part1/hist block
#define NCHUNK ((NE + CHUNK - 1) / CHUNK)  // 1172
#define P2CAP 8192                         // part2 LDS capacity (mean 6144, sd 78)

// ---------------------------------------------------------------------------
// K1: y[n, c] = sum_f x[n, f] * W[f, c].  2 threads per node (16 ch each).
// ---------------------------------------------------------------------------
__global__ __launch_bounds__(256) void gemm_xw(const float* __restrict__ x,
                                               const float* __restrict__ W,
                                               float* __restrict__ y) {
    __shared__ float Ws[F * C];
    for (int i = threadIdx.x; i < F * C; i += 256) Ws[i] = W[i];
    __syncthreads();

    const int g = blockIdx.x * 256 + threadIdx.x;
    if (g >= N_NODES * 2) return;
    const int node = g >> 1;
    const int h = (g & 1) * 16;

    const float4* xp = (const float4*)(x + (size_t)node * F);
    float acc[16];
#pragma unroll
    for (int c = 0; c < 16; c++) acc[c] = 0.f;

#pragma unroll
    for (int i = 0; i < 16; i++) {
        float4 v = xp[i];
        const int f = i * 4;
#pragma unroll
        for (int c = 0; c < 16; c++) {
            acc[c] += v.x * Ws[(f + 0) * C + h + c];
            acc[c] += v.y * Ws[(f + 1) * C + h + c];
            acc[c] += v.z * Ws[(f + 2) * C + h + c];
            acc[c] += v.w * Ws[(f + 3) * C + h + c];
        }
    }

    float4* yo = (float4*)(y + (size_t)node * C + h);
#pragma unroll
    for (int i = 0; i < 4; i++)
        yo[i] = make_float4(acc[4 * i], acc[4 * i + 1], acc[4 * i + 2], acc[4 * i + 3]);
}

// ---------------------------------------------------------------------------
// K2: coarse histogram — LDS-aggregated, int4 edge loads (4 edges/thread/grp).
// ---------------------------------------------------------------------------
__global__ __launch_bounds__(256) void hist_c(const int* __restrict__ rows,
                                              int* __restrict__ hcnt) {
    __shared__ int hh[NBUCK];
    for (int i = threadIdx.x; i < NBUCK; i += 256) hh[i] = 0;
    __syncthreads();
    const int base = blockIdx.x * CHUNK;
#pragma unroll
    for (int j = 0; j < 4; j++) {
        const int e = base + j * 1024 + threadIdx.x * 4;
        if (e + 3 < NE) {
            const int4 r4 = *(const int4*)(rows + e);
            atomicAdd(&hh[r4.x >> 7], 1);
            atomicAdd(&hh[r4.y >> 7], 1);
            atomicAdd(&hh[r4.z >> 7], 1);
            atomicAdd(&hh[r4.w >> 7], 1);
        }
    }
    __syncthreads();
    for (int i = threadIdx.x; i < NBUCK; i += 256) {
        const int cc = hh[i];
        if (cc) atomicAdd(&hcnt[i], cc);
    }
}

// ---------------------------------------------------------------------------
// K3: single-block scan of 782 bucket counts -> bstart, bcur, rs sentinel.
// ---------------------------------------------------------------------------
__global__ __launch_bounds__(256) void scan_c(const int* __restrict__ hcnt,
                                              int* __restrict__ bstart,
                                              int* __restrict__ bcur,
                                              int* __restrict__ rs_start) {
    __shared__ int sA[1024], sB[1024];
    const int tid = threadIdx.x;
    for (int i = tid; i < 1024; i += 256) sA[i] = (i < NBUCK) ? hcnt[i] : 0;
    __syncthreads();
    int* src = sA;
    int* dst = sB;
    for (int d = 1; d < 1024; d <<= 1) {
        for (int i = tid; i < 1024; i += 256) {
            int v = src[i];
            if (i >= d) v += src[i - d];
            dst[i] = v;
        }
        __syncthreads();
        int* t = src; src = dst; dst = t;
    }
    for (int i = tid; i < NBUCK; i += 256) {
        const int excl = (i == 0) ? 0 : src[i - 1];
        bstart[i] = excl;
        bcur[i] = excl;
    }
    if (tid == 0) {
        bstart[NBUCK] = NE;
        rs_start[NKEY] = NE;
    }
}

// ---------------------------------------------------------------------------
// K4: part1 — LDS-staged coarse partition. int4/float4 edge loads; in-place
// scan (sA reused) shaves 4KB -> 50.1KB LDS -> 3 blocks/CU (was 2).
// bucket = row>>7. Entry: { (key&511)<<17 | col , val*alpha }.
// ---------------------------------------------------------------------------
__global__ __launch_bounds__(256) void part1_k(const float* __restrict__ vals,
                                               const int* __restrict__ rows,
                                               const int* __restrict__ cols,
                                               const float* __restrict__ alpha,
                                               int* __restrict__ bcur,
                                               int2* __restrict__ edgebuf) {
    __shared__ int sA[1024];                 // counts -> (in-place) inclusive scan
    __shared__ int wtot[4];
    __shared__ int lpos[NBUCK];
    __shared__ int lbase[NBUCK];
    __shared__ int2 stage[CHUNK];            // 32 KB
    __shared__ unsigned short sbin[CHUNK];   // 8 KB

    const int tid = threadIdx.x;
    const int base = blockIdx.x * CHUNK;

    for (int i = tid; i < 1024; i += 256) sA[i] = 0;
    __syncthreads();

    int kj[16], cj[16];
    float wj[16];
#pragma unroll
    for (int j = 0; j < 4; j++) {
        const int e = base + j * 1024 + tid * 4;
        if (e + 3 < NE) {  // E, NE multiples of 4: group uniform hop, no straddle
            const int4   r4 = *(const int4*)(rows + e);
            const int4   c4 = *(const int4*)(cols + e);
            const float4 v4 = *(const float4*)(vals + e);
            const float ak = alpha[(e >= 2 * E) ? 2 : (e >= E) ? 1 : 0];
            kj[j * 4 + 0] = r4.x * NSLICE + c4.x / SLICEW; cj[j * 4 + 0] = c4.x; wj[j * 4 + 0] = v4.x * ak;
            kj[j * 4 + 1] = r4.y * NSLICE + c4.y / SLICEW; cj[j * 4 + 1] = c4.y; wj[j * 4 + 1] = v4.y * ak;
            kj[j * 4 + 2] = r4.z * NSLICE + c4.z / SLICEW; cj[j * 4 + 2] = c4.z; wj[j * 4 + 2] = v4.z * ak;
            kj[j * 4 + 3] = r4.w * NSLICE + c4.w / SLICEW; cj[j * 4 + 3] = c4.w; wj[j * 4 + 3] = v4.w * ak;
            atomicAdd(&sA[kj[j * 4 + 0] >> 9], 1);
            atomicAdd(&sA[kj[j * 4 + 1] >> 9], 1);
            atomicAdd(&sA[kj[j * 4 + 2] >> 9], 1);
            atomicAdd(&sA[kj[j * 4 + 3] >> 9], 1);
        } else {
            kj[j * 4 + 0] = kj[j * 4 + 1] = kj[j * 4 + 2] = kj[j * 4 + 3] = -1;
        }
    }
    __syncthreads();

    {   // wave-scan, in-place in sA: read -> barrier -> write-back
        const int lane = tid & 63;
        const int w = tid >> 6;
        const int b4 = tid * 4;
        const int a0 = sA[b4], a1 = sA[b4 + 1], a2 = sA[b4 + 2], a3 = sA[b4 + 3];
        const int l1 = a0 + a1, l2 = l1 + a2, l3 = l2 + a3;
        int sc = l3;
#pragma unroll
        for (int d = 1; d < 64; d <<= 1) {
            int u = __shfl_up(sc, d);
            if (lane >= d) sc += u;
        }
        if (lane == 63) wtot[w] = sc;
        __syncthreads();   // all reads of sA done; wtot visible
        int wb = 0;
#pragma unroll
        for (int q = 0; q < 4; q++)
            if (q < w) wb += wtot[q];
        const int tb = wb + sc - l3;
        sA[b4] = tb + a0; sA[b4 + 1] = tb + l1; sA[b4 + 2] = tb + l2; sA[b4 + 3] = tb + l3;
    }
    __syncthreads();

    for (int i = tid; i < NBUCK; i += 256) {
        const int excl = (i == 0) ? 0 : sA[i - 1];
        const int cnt = sA[i] - excl;
        lpos[i] = excl;
        if (cnt) lbase[i] = atomicAdd(&bcur[i], cnt);
    }
    __syncthreads();

#pragma unroll
    for (int j = 0; j < 16; j++) {
        if (kj[j] >= 0) {
            const int b = kj[j] >> 9;
            const int p = atomicAdd(&lpos[b], 1);
            stage[p] = make_int2(((kj[j] & (KPB - 1)) << 17) | cj[j],
                                 __float_as_int(wj[j]));
            sbin[p] = (unsigned short)b;
        }
    }
    __syncthreads();

    const int total = sA[1023];
    for (int p = tid; p < total; p += 256) {
        const int b = sbin[p];
        const int excl = (b == 0) ? 0 : sA[b - 1];
        edgebuf[lbase[b] + (p - excl)] = stage[p];
    }
}

// ---------------------------------------------------------------------------
// K5: part2 — per-bucket in-LDS counting sort. 512 threads (16 waves/CU at
// 2 blocks/CU) double the per-bucket parallelism.
// ---------------------------------------------------------------------------
__global__ __launch_bounds__(512) void part2_k(const int* __restrict__ bstart,
                                               int* __restrict__ rs_start,
                                               int2* __restrict__ edgebuf) {
    __shared__ int2 sstage[P2CAP];   // 64 KB
    __shared__ int sh[KPB];          // counts
    __shared__ int sg[KPB];          // inclusive scan
    __shared__ int wtot[8];
    __shared__ int lbin[KPB];        // write cursors

    const int tid = threadIdx.x;
    const int b = blockIdx.x;
    const int bs = bstart[b];
    const int be = bstart[b + 1];
    const int n = be - bs;

    for (int k = tid; k < KPB; k += 512) sh[k] = 0;
    __syncthreads();

    if (n <= P2CAP) {
        for (int i = tid; i < n; i += 512) {
            const int2 e = edgebuf[bs + i];
            sstage[i] = e;
            atomicAdd(&sh[((unsigned)e.x) >> 17], 1);
        }
    }
    __syncthreads();

    {   // wave-scan: 512 threads, 1 sub-key each
        const int lane = tid & 63;
        const int w = tid >> 6;
        const int a0 = sh[tid];
        int sc = a0;
#pragma unroll
        for (int d = 1; d < 64; d <<= 1) {
            int u = __shfl_up(sc, d);
            if (lane >= d) sc += u;
        }
        if (lane == 63) wtot[w] = sc;
        __syncthreads();
        int wb = 0;
#pragma unroll
        for (int q = 0; q < 8; q++)
            if (q < w) wb += wtot[q];
        sg[tid] = wb + sc;
    }
    __syncthreads();

    for (int k = tid; k < KPB; k += 512) {
        const int st = bs + ((k == 0) ? 0 : sg[k - 1]);
        lbin[k] = st;
        const int idx = (b << 9) + k;
        if (idx < NKEY) rs_start[idx] = st;
    }
    __syncthreads();

    if (n > P2CAP) return;  // 26-sigma impossible

    for (int i = tid; i < n; i += 512) {
        const int2 e = sstage[i];
        const int sub = ((unsigned)e.x) >> 17;
        const int pos = atomicAdd(&lbin[sub], 1);
        edgebuf[pos] = e;
    }
}

// ---------------------------------------------------------------------------
// K6: gather — half-wave per (row, slice) task, 8 tasks/block; 8-deep then
// 4-deep then scalar tail (PROVEN r10 kernel, 144us, byte-identical).
// ---------------------------------------------------------------------------
__global__ __launch_bounds__(256) void gathers9_k(const long long* __restrict__ eb,
                                                  const int* __restrict__ rs_start,
                                                  const float* __restrict__ y,
                                                  const float* __restrict__ bias,
                                                  float* __restrict__ out) {
    const int blk = blockIdx.x;
    const int s = blk & (NSLICE - 1);
    const int row = (blk >> 2) * 8 + (threadIdx.x >> 5);
    const int c = threadIdx.x & 31;
    const int key = row * NSLICE + s;
    const int st = rs_start[key];
    const int en = rs_start[key + 1];

    float acc = (s == 0) ? bias[c] : 0.f;

    int i = st;
    for (; i + 8 <= en; i += 8) {
        const long long l0 = __builtin_nontemporal_load(&eb[i + 0]);
        const long long l1 = __builtin_nontemporal_load(&eb[i + 1]);
        const long long l2 = __builtin_nontemporal_load(&eb[i + 2]);
        const long long l3 = __builtin_nontemporal_load(&eb[i + 3]);
        const long long l4 = __builtin_nontemporal_load(&eb[i + 4]);
        const long long l5 = __builtin_nontemporal_load(&eb[i + 5]);
        const long long l6 = __builtin_nontemporal_load(&eb[i + 6]);
        const long long l7 = __builtin_nontemporal_load(&eb[i + 7]);
        const float y0 = y[(((int)l0) & 0x1FFFF) * C + c];
        const float y1 = y[(((int)l1) & 0x1FFFF) * C + c];
        const float y2 = y[(((int)l2) & 0x1FFFF) * C + c];
        const float y3 = y[(((int)l3) & 0x1FFFF) * C + c];
        const float y4 = y[(((int)l4) & 0x1FFFF) * C + c];
        const float y5 = y[(((int)l5) & 0x1FFFF) * C + c];
        const float y6 = y[(((int)l6) & 0x1FFFF) * C + c];
        const float y7 = y[(((int)l7) & 0x1FFFF) * C + c];
        acc += __int_as_float((int)(l0 >> 32)) * y0;
        acc += __int_as_float((int)(l1 >> 32)) * y1;
        acc += __int_as_float((int)(l2 >> 32)) * y2;
        acc += __int_as_float((int)(l3 >> 32)) * y3;
        acc += __int_as_float((int)(l4 >> 32)) * y4;
        acc += __int_as_float((int)(l5 >> 32)) * y5;
        acc += __int_as_float((int)(l6 >> 32)) * y6;
        acc += __int_as_float((int)(l7 >> 32)) * y7;
    }
    for (; i + 4 <= en; i += 4) {
        const long long l0 = __builtin_nontemporal_load(&eb[i + 0]);
        const long long l1 = __builtin_nontemporal_load(&eb[i + 1]);
        const long long l2 = __builtin_nontemporal_load(&eb[i + 2]);
        const long long l3 = __builtin_nontemporal_load(&eb[i + 3]);
        const float y0 = y[(((int)l0) & 0x1FFFF) * C + c];
        const float y1 = y[(((int)l1) & 0x1FFFF) * C + c];
        const float y2 = y[(((int)l2) & 0x1FFFF) * C + c];
        const float y3 = y[(((int)l3) & 0x1FFFF) * C + c];
        acc += __int_as_float((int)(l0 >> 32)) * y0;
        acc += __int_as_float((int)(l1 >> 32)) * y1;
        acc += __int_as_float((int)(l2 >> 32)) * y2;
        acc += __int_as_float((int)(l3 >> 32)) * y3;
    }
    for (; i < en; i++) {
        const long long l0 = __builtin_nontemporal_load(&eb[i]);
        acc += __int_as_float((int)(l0 >> 32)) * y[(((int)l0) & 0x1FFFF) * C + c];
    }

    unsafeAtomicAdd(out + (size_t)row * C + c, acc);
}

// ---------------------------------------------------------------------------
// Fallback (proven): atomic scatter if workspace too small.
// ---------------------------------------------------------------------------
__global__ __launch_bounds__(256) void scatter_edges(
    const float* __restrict__ vals, const int* __restrict__ rows,
    const int* __restrict__ cols, const float* __restrict__ alpha,
    const float* __restrict__ y, float* __restrict__ out_acc) {
    const int t = blockIdx.x * 256 + threadIdx.x;
    const int e = t >> 5;
    const int c = t & 31;
    if (e >= KH * E) return;
    const int k = (e >= 2 * E) ? 2 : (e >= E) ? 1 : 0;
    const float w = vals[e] * alpha[k];
    const float yv = y[(size_t)cols[e] * C + c];
    unsafeAtomicAdd(out_acc + (size_t)rows[e] * C + c, w * yv);
}

__global__ __launch_bounds__(256) void finalize_k(float* __restrict__ out,
                                                  const float* __restrict__ bias) {
    const int idx = (blockIdx.x * 256 + threadIdx.x) * 4;
    if (idx >= N_NODES * C) return;
    const int c0 = idx & (C - 1);
    float4 v = *(float4*)(out + idx);
    v.x += bias[c0 + 0];
    v.y += bias[c0 + 1];
    v.z += bias[c0 + 2];
    v.w += bias[c0 + 3];
    *(float4*)(out + idx) = v;
}

// ---------------------------------------------------------------------------
extern "C" void kernel_launch(void* const* d_in, const int* in_sizes, int n_in,
                              void* d_out, int out_size, void* d_ws, size_t ws_size,
                              hipStream_t stream) {
    const float* x         = (const float*)d_in[0];
    const float* edge_vals = (const float*)d_in[1];
    const float* W         = (const float*)d_in[2];
    const float* b         = (const float*)d_in[3];
    const float* alpha     = (const float*)d_in[4];
    const int*   edge_rows = (const int*)d_in[5];
    const int*   edge_cols = (const int*)d_in[6];
    float*       out       = (float*)d_out;

    // Workspace layout (proven to fit: ~52.81 MB)
    const size_t offY   = 0;                                   // 12,800,000
    const size_t offEB  = (size_t)N_NODES * C * 4;             // +38,400,000
    const size_t offRS  = offEB + (size_t)NE * 8;              // 51,200,000
    const size_t offBS  = offRS + (((size_t)(NKEY + 1) * 4 + 255) & ~(size_t)255);
    const size_t offBC  = offBS + (((NBUCK + 1) * 4 + 255) & ~(size_t)255);
    const size_t offHC  = offBC + ((NBUCK * 4 + 255) & ~(size_t)255);
    const size_t need   = offHC + (size_t)NBUCK * 4;

    float* y = (float*)((char*)d_ws + offY);

    gemm_xw<<<(N_NODES * 2 + 255) / 256, 256, 0, stream>>>(x, W, y);

    if (ws_size >= need) {
        int2* edgebuf  = (int2*)((char*)d_ws + offEB);
        int*  rs_start = (int*)((char*)d_ws + offRS);
        int*  bstart   = (int*)((char*)d_ws + offBS);
        int*  bcur     = (int*)((char*)d_ws + offBC);
        int*  hcnt     = (int*)((char*)d_ws + offHC);

        hipMemsetAsync(hcnt, 0, (size_t)NBUCK * 4, stream);
        hipMemsetAsync(out, 0, (size_t)N_NODES * C * sizeof(float), stream);

        hist_c<<<NCHUNK, 256, 0, stream>>>(edge_rows, hcnt);
        scan_c<<<1, 256, 0, stream>>>(hcnt, bstart, bcur, rs_start);
        part1_k<<<NCHUNK, 256, 0, stream>>>(edge_vals, edge_rows, edge_cols,
                                            alpha, bcur, edgebuf);
        part2_k<<<NBUCK, 512, 0, stream>>>(bstart, rs_start, edgebuf);
        gathers9_k<<<(N_NODES / 8) * NSLICE, 256, 0, stream>>>(
            (const long long*)edgebuf, rs_start, y, b, out);
    } else {
        hipMemsetAsync(out, 0, (size_t)N_NODES * C * sizeof(float), stream);
        const long long scatter_threads = (long long)KH * E * C;
        const int scatter_blocks = (int)((scatter_threads + 255) / 256);
        scatter_edges<<<scatter_blocks, 256, 0, stream>>>(
            edge_vals, edge_rows, edge_cols, alpha, y, out);
        finalize_k<<<(N_NODES * C / 4 + 255) / 256, 256, 0, stream>>>(out, b);
    }
}

// Round 12
// 355.373 us; speedup vs baseline: 1.3185x; 1.0655x over previous
//
#include <hip/hip_runtime.h>

#define N_NODES 100000
#define F 64
#define C 32
#define KH 3
#define E 1600000
#define NE (KH * E)                        // 4,800,000 edges

#define NSLICE 4                           // y col-slices; 3.2 MB < 4 MB L2/XCD
#define SLICEW 25000
#define NKEY (N_NODES * NSLICE)            // 400,000 sort keys (row*4 + slice)
#define KPB 512                            // keys per coarse bucket (= 128 rows)
#define NBUCK ((NKEY + KPB - 1) / KPB)     // 782
#define HCHUNK 4096                        // edges per hist block
#define NHCHUNK ((NE + HCHUNK - 1) / HCHUNK)   // 1172
#define CHUNK1 8192                        // edges per part1 block (runs 4->8)
#define NCHUNK1 ((NE + CHUNK1 - 1) / CHUNK1)   // 586
#define P2CAP 8192                         // part2 LDS capacity (mean 6144, sd 78)
#define GEMM_BLOCKS ((N_NODES * 2 + 255) / 256) // 782

// ---------------------------------------------------------------------------
// K1: FUSED gemm + coarse histogram (independent work, disjoint block ranges).
// blocks [0, GEMM_BLOCKS): y = x @ W (2 threads/node, 16 ch each).
// blocks [GEMM_BLOCKS, +NHCHUNK): LDS-aggregated histogram, bucket = row>>7.
// ---------------------------------------------------------------------------
__global__ __launch_bounds__(256) void gemm_hist_k(const float* __restrict__ x,
                                                   const float* __restrict__ W,
                                                   float* __restrict__ y,
                                                   const int* __restrict__ rows,
                                                   int* __restrict__ hcnt) {
    __shared__ float smem[F * C];  // 8 KB; reused as int hh[NBUCK] in hist role

    if (blockIdx.x < GEMM_BLOCKS) {
        float* Ws = smem;
        for (int i = threadIdx.x; i < F * C; i += 256) Ws[i] = W[i];
        __syncthreads();

        const int g = blockIdx.x * 256 + threadIdx.x;
        if (g >= N_NODES * 2) return;
        const int node = g >> 1;
        const int h = (g & 1) * 16;

        const float4* xp = (const float4*)(x + (size_t)node * F);
        float acc[16];
#pragma unroll
        for (int c = 0; c < 16; c++) acc[c] = 0.f;

#pragma unroll
        for (int i = 0; i < 16; i++) {
            float4 v = xp[i];
            const int f = i * 4;
#pragma unroll
            for (int c = 0; c < 16; c++) {
                acc[c] += v.x * Ws[(f + 0) * C + h + c];
                acc[c] += v.y * Ws[(f + 1) * C + h + c];
                acc[c] += v.z * Ws[(f + 2) * C + h + c];
                acc[c] += v.w * Ws[(f + 3) * C + h + c];
            }
        }

        float4* yo = (float4*)(y + (size_t)node * C + h);
#pragma unroll
        for (int i = 0; i < 4; i++)
            yo[i] = make_float4(acc[4 * i], acc[4 * i + 1], acc[4 * i + 2], acc[4 * i + 3]);
    } else {
        int* hh = (int*)smem;
        for (int i = threadIdx.x; i < NBUCK; i += 256) hh[i] = 0;
        __syncthreads();
        const int base = (blockIdx.x - GEMM_BLOCKS) * HCHUNK;
#pragma unroll
        for (int j = 0; j < 4; j++) {
            const int e = base + j * 1024 + threadIdx.x * 4;
            if (e + 3 < NE) {
                const int4 r4 = *(const int4*)(rows + e);
                atomicAdd(&hh[r4.x >> 7], 1);
                atomicAdd(&hh[r4.y >> 7], 1);
                atomicAdd(&hh[r4.z >> 7], 1);
                atomicAdd(&hh[r4.w >> 7], 1);
            }
        }
        __syncthreads();
        for (int i = threadIdx.x; i < NBUCK; i += 256) {
            const int cc = hh[i];
            if (cc) atomicAdd(&hcnt[i], cc);
        }
    }
}

// ---------------------------------------------------------------------------
// K3: single-block scan of 782 bucket counts -> bstart, bcur, rs sentinel.
// ---------------------------------------------------------------------------
__global__ __launch_bounds__(256) void scan_c(const int* __restrict__ hcnt,
                                              int* __restrict__ bstart,
                                              int* __restrict__ bcur,
                                              int* __restrict__ rs_start) {
    __shared__ int sA[1024], sB[1024];
    const int tid = threadIdx.x;
    for (int i = tid; i < 1024; i += 256) sA[i] = (i < NBUCK) ? hcnt[i] : 0;
    __syncthreads();
    int* src = sA;
    int* dst = sB;
    for (int d = 1; d < 1024; d <<= 1) {
        for (int i = tid; i < 1024; i += 256) {
            int v = src[i];
            if (i >= d) v += src[i - d];
            dst[i] = v;
        }
        __syncthreads();
        int* t = src; src = dst; dst = t;
    }
    for (int i = tid; i < NBUCK; i += 256) {
        const int excl = (i == 0) ? 0 : src[i - 1];
        bstart[i] = excl;
        bcur[i] = excl;
    }
    if (tid == 0) {
        bstart[NBUCK] = NE;
        rs_start[NKEY] = NE;
    }
}

// ---------------------------------------------------------------------------
// K4: part1 — LDS-staged coarse partition. CHUNK1=8192 / 512 threads: flush
// runs double (4 -> 8 entries = 64B), halving random-write line amplification.
// LDS ~90 KB (>64KB/WG proven by part2). bucket = row>>7.
// Entry: { (key&511)<<17 | col , val*alpha }.
// ---------------------------------------------------------------------------
__global__ __launch_bounds__(512) void part1_k(const float* __restrict__ vals,
                                               const int* __restrict__ rows,
                                               const int* __restrict__ cols,
                                               const float* __restrict__ alpha,
                                               int* __restrict__ bcur,
                                               int2* __restrict__ edgebuf) {
    __shared__ int sA[1024];                 // counts -> (in-place) inclusive scan
    __shared__ int wtot[8];
    __shared__ int lpos[NBUCK];
    __shared__ int lbase[NBUCK];
    __shared__ int2 stage[CHUNK1];           // 64 KB
    __shared__ unsigned short sbin[CHUNK1];  // 16 KB

    const int tid = threadIdx.x;
    const int base = blockIdx.x * CHUNK1;

    for (int i = tid; i < 1024; i += 512) sA[i] = 0;
    __syncthreads();

    int kj[16], cj[16];
    float wj[16];
#pragma unroll
    for (int j = 0; j < 4; j++) {
        const int e = base + j * 2048 + tid * 4;
        if (e + 3 < NE) {  // E, NE multiples of 4: group uniform hop, no straddle
            const int4   r4 = *(const int4*)(rows + e);
            const int4   c4 = *(const int4*)(cols + e);
            const float4 v4 = *(const float4*)(vals + e);
            const float ak = alpha[(e >= 2 * E) ? 2 : (e >= E) ? 1 : 0];
            kj[j * 4 + 0] = r4.x * NSLICE + c4.x / SLICEW; cj[j * 4 + 0] = c4.x; wj[j * 4 + 0] = v4.x * ak;
            kj[j * 4 + 1] = r4.y * NSLICE + c4.y / SLICEW; cj[j * 4 + 1] = c4.y; wj[j * 4 + 1] = v4.y * ak;
            kj[j * 4 + 2] = r4.z * NSLICE + c4.z / SLICEW; cj[j * 4 + 2] = c4.z; wj[j * 4 + 2] = v4.z * ak;
            kj[j * 4 + 3] = r4.w * NSLICE + c4.w / SLICEW; cj[j * 4 + 3] = c4.w; wj[j * 4 + 3] = v4.w * ak;
            atomicAdd(&sA[kj[j * 4 + 0] >> 9], 1);
            atomicAdd(&sA[kj[j * 4 + 1] >> 9], 1);
            atomicAdd(&sA[kj[j * 4 + 2] >> 9], 1);
            atomicAdd(&sA[kj[j * 4 + 3] >> 9], 1);
        } else {
            kj[j * 4 + 0] = kj[j * 4 + 1] = kj[j * 4 + 2] = kj[j * 4 + 3] = -1;
        }
    }
    __syncthreads();

    {   // wave-scan over 1024 bins, in-place in sA (read -> barrier -> write)
        const int lane = tid & 63;
        const int w = tid >> 6;
        const int b2 = tid * 2;
        const int a0 = sA[b2], a1 = sA[b2 + 1];
        const int l1 = a0 + a1;
        int sc = l1;
#pragma unroll
        for (int d = 1; d < 64; d <<= 1) {
            int u = __shfl_up(sc, d);
            if (lane >= d) sc += u;
        }
        if (lane == 63) wtot[w] = sc;
        __syncthreads();   // all reads of sA done; wtot visible
        int wb = 0;
#pragma unroll
        for (int q = 0; q < 8; q++)
            if (q < w) wb += wtot[q];
        const int tb = wb + sc - l1;
        sA[b2] = tb + a0; sA[b2 + 1] = tb + l1;
    }
    __syncthreads();

    for (int i = tid; i < NBUCK; i += 512) {
        const int excl = (i == 0) ? 0 : sA[i - 1];
        const int cnt = sA[i] - excl;
        lpos[i] = excl;
        if (cnt) lbase[i] = atomicAdd(&bcur[i], cnt);
    }
    __syncthreads();

#pragma unroll
    for (int j = 0; j < 16; j++) {
        if (kj[j] >= 0) {
            const int b = kj[j] >> 9;
            const int p = atomicAdd(&lpos[b], 1);
            stage[p] = make_int2(((kj[j] & (KPB - 1)) << 17) | cj[j],
                                 __float_as_int(wj[j]));
            sbin[p] = (unsigned short)b;
        }
    }
    __syncthreads();

    const int total = sA[1023];
    for (int p = tid; p < total; p += 512) {
        const int b = sbin[p];
        const int excl = (b == 0) ? 0 : sA[b - 1];
        edgebuf[lbase[b] + (p - excl)] = stage[p];
    }
}

// ---------------------------------------------------------------------------
// K5: part2 — per-bucket in-LDS counting sort. 512 threads (proven r11).
// ---------------------------------------------------------------------------
__global__ __launch_bounds__(512) void part2_k(const int* __restrict__ bstart,
                                               int* __restrict__ rs_start,
                                               int2* __restrict__ edgebuf) {
    __shared__ int2 sstage[P2CAP];   // 64 KB
    __shared__ int sh[KPB];          // counts
    __shared__ int sg[KPB];          // inclusive scan
    __shared__ int wtot[8];
    __shared__ int lbin[KPB];        // write cursors

    const int tid = threadIdx.x;
    const int b = blockIdx.x;
    const int bs = bstart[b];
    const int be = bstart[b + 1];
    const int n = be - bs;

    for (int k = tid; k < KPB; k += 512) sh[k] = 0;
    __syncthreads();

    if (n <= P2CAP) {
        for (int i = tid; i < n; i += 512) {
            const int2 e = edgebuf[bs + i];
            sstage[i] = e;
            atomicAdd(&sh[((unsigned)e.x) >> 17], 1);
        }
    }
    __syncthreads();

    {   // wave-scan: 512 threads, 1 sub-key each
        const int lane = tid & 63;
        const int w = tid >> 6;
        const int a0 = sh[tid];
        int sc = a0;
#pragma unroll
        for (int d = 1; d < 64; d <<= 1) {
            int u = __shfl_up(sc, d);
            if (lane >= d) sc += u;
        }
        if (lane == 63) wtot[w] = sc;
        __syncthreads();
        int wb = 0;
#pragma unroll
        for (int q = 0; q < 8; q++)
            if (q < w) wb += wtot[q];
        sg[tid] = wb + sc;
    }
    __syncthreads();

    for (int k = tid; k < KPB; k += 512) {
        const int st = bs + ((k == 0) ? 0 : sg[k - 1]);
        lbin[k] = st;
        const int idx = (b << 9) + k;
        if (idx < NKEY) rs_start[idx] = st;
    }
    __syncthreads();

    if (n > P2CAP) return;  // 26-sigma impossible

    for (int i = tid; i < n; i += 512) {
        const int2 e = sstage[i];
        const int sub = ((unsigned)e.x) >> 17;
        const int pos = atomicAdd(&lbin[sub], 1);
        edgebuf[pos] = e;
    }
}

// ---------------------------------------------------------------------------
// K6: gather — half-wave per (row, slice) task, 8 tasks/block; 8-deep then
// 4-deep then scalar tail (PROVEN r10/r11 kernel, 144us, byte-identical).
// ---------------------------------------------------------------------------
__global__ __launch_bounds__(256) void gathers9_k(const long long* __restrict__ eb,
                                                  const int* __restrict__ rs_start,
                                                  const float* __restrict__ y,
                                                  const float* __restrict__ bias,
                                                  float* __restrict__ out) {
    const int blk = blockIdx.x;
    const int s = blk & (NSLICE - 1);
    const int row = (blk >> 2) * 8 + (threadIdx.x >> 5);
    const int c = threadIdx.x & 31;
    const int key = row * NSLICE + s;
    const int st = rs_start[key];
    const int en = rs_start[key + 1];

    float acc = (s == 0) ? bias[c] : 0.f;

    int i = st;
    for (; i + 8 <= en; i += 8) {
        const long long l0 = __builtin_nontemporal_load(&eb[i + 0]);
        const long long l1 = __builtin_nontemporal_load(&eb[i + 1]);
        const long long l2 = __builtin_nontemporal_load(&eb[i + 2]);
        const long long l3 = __builtin_nontemporal_load(&eb[i + 3]);
        const long long l4 = __builtin_nontemporal_load(&eb[i + 4]);
        const long long l5 = __builtin_nontemporal_load(&eb[i + 5]);
        const long long l6 = __builtin_nontemporal_load(&eb[i + 6]);
        const long long l7 = __builtin_nontemporal_load(&eb[i + 7]);
        const float y0 = y[(((int)l0) & 0x1FFFF) * C + c];
        const float y1 = y[(((int)l1) & 0x1FFFF) * C + c];
        const float y2 = y[(((int)l2) & 0x1FFFF) * C + c];
        const float y3 = y[(((int)l3) & 0x1FFFF) * C + c];
        const float y4 = y[(((int)l4) & 0x1FFFF) * C + c];
        const float y5 = y[(((int)l5) & 0x1FFFF) * C + c];
        const float y6 = y[(((int)l6) & 0x1FFFF) * C + c];
        const float y7 = y[(((int)l7) & 0x1FFFF) * C + c];
        acc += __int_as_float((int)(l0 >> 32)) * y0;
        acc += __int_as_float((int)(l1 >> 32)) * y1;
        acc += __int_as_float((int)(l2 >> 32)) * y2;
        acc += __int_as_float((int)(l3 >> 32)) * y3;
        acc += __int_as_float((int)(l4 >> 32)) * y4;
        acc += __int_as_float((int)(l5 >> 32)) * y5;
        acc += __int_as_float((int)(l6 >> 32)) * y6;
        acc += __int_as_float((int)(l7 >> 32)) * y7;
    }
    for (; i + 4 <= en; i += 4) {
        const long long l0 = __builtin_nontemporal_load(&eb[i + 0]);
        const long long l1 = __builtin_nontemporal_load(&eb[i + 1]);
        const long long l2 = __builtin_nontemporal_load(&eb[i + 2]);
        const long long l3 = __builtin_nontemporal_load(&eb[i + 3]);
        const float y0 = y[(((int)l0) & 0x1FFFF) * C + c];
        const float y1 = y[(((int)l1) & 0x1FFFF) * C + c];
        const float y2 = y[(((int)l2) & 0x1FFFF) * C + c];
        const float y3 = y[(((int)l3) & 0x1FFFF) * C + c];
        acc += __int_as_float((int)(l0 >> 32)) * y0;
        acc += __int_as_float((int)(l1 >> 32)) * y1;
        acc += __int_as_float((int)(l2 >> 32)) * y2;
        acc += __int_as_float((int)(l3 >> 32)) * y3;
    }
    for (; i < en; i++) {
        const long long l0 = __builtin_nontemporal_load(&eb[i]);
        acc += __int_as_float((int)(l0 >> 32)) * y[(((int)l0) & 0x1FFFF) * C + c];
    }

    unsafeAtomicAdd(out + (size_t)row * C + c, acc);
}

// ---------------------------------------------------------------------------
// Fallback (proven): atomic scatter if workspace too small.
// ---------------------------------------------------------------------------
__global__ __launch_bounds__(256) void scatter_edges(
    const float* __restrict__ vals, const int* __restrict__ rows,
    const int* __restrict__ cols, const float* __restrict__ alpha,
    const float* __restrict__ y, float* __restrict__ out_acc) {
    const int t = blockIdx.x * 256 + threadIdx.x;
    const int e = t >> 5;
    const int c = t & 31;
    if (e >= KH * E) return;
    const int k = (e >= 2 * E) ? 2 : (e >= E) ? 1 : 0;
    const float w = vals[e] * alpha[k];
    const float yv = y[(size_t)cols[e] * C + c];
    unsafeAtomicAdd(out_acc + (size_t)rows[e] * C + c, w * yv);
}

__global__ __launch_bounds__(256) void gemm_only_k(const float* __restrict__ x,
                                                   const float* __restrict__ W,
                                                   float* __restrict__ y) {
    __shared__ float Ws[F * C];
    for (int i = threadIdx.x; i < F * C; i += 256) Ws[i] = W[i];
    __syncthreads();
    const int g = blockIdx.x * 256 + threadIdx.x;
    if (g >= N_NODES * 2) return;
    const int node = g >> 1;
    const int h = (g & 1) * 16;
    const float4* xp = (const float4*)(x + (size_t)node * F);
    float acc[16];
#pragma unroll
    for (int c = 0; c < 16; c++) acc[c] = 0.f;
#pragma unroll
    for (int i = 0; i < 16; i++) {
        float4 v = xp[i];
        const int f = i * 4;
#pragma unroll
        for (int c = 0; c < 16; c++) {
            acc[c] += v.x * Ws[(f + 0) * C + h + c];
            acc[c] += v.y * Ws[(f + 1) * C + h + c];
            acc[c] += v.z * Ws[(f + 2) * C + h + c];
            acc[c] += v.w * Ws[(f + 3) * C + h + c];
        }
    }
    float4* yo = (float4*)(y + (size_t)node * C + h);
#pragma unroll
    for (int i = 0; i < 4; i++)
        yo[i] = make_float4(acc[4 * i], acc[4 * i + 1], acc[4 * i + 2], acc[4 * i + 3]);
}

__global__ __launch_bounds__(256) void finalize_k(float* __restrict__ out,
                                                  const float* __restrict__ bias) {
    const int idx = (blockIdx.x * 256 + threadIdx.x) * 4;
    if (idx >= N_NODES * C) return;
    const int c0 = idx & (C - 1);
    float4 v = *(float4*)(out + idx);
    v.x += bias[c0 + 0];
    v.y += bias[c0 + 1];
    v.z += bias[c0 + 2];
    v.w += bias[c0 + 3];
    *(float4*)(out + idx) = v;
}

// ---------------------------------------------------------------------------
extern "C" void kernel_launch(void* const* d_in, const int* in_sizes, int n_in,
                              void* d_out, int out_size, void* d_ws, size_t ws_size,
                              hipStream_t stream) {
    const float* x         = (const float*)d_in[0];
    const float* edge_vals = (const float*)d_in[1];
    const float* W         = (const float*)d_in[2];
    const float* b         = (const float*)d_in[3];
    const float* alpha     = (const float*)d_in[4];
    const int*   edge_rows = (const int*)d_in[5];
    const int*   edge_cols = (const int*)d_in[6];
    float*       out       = (float*)d_out;

    // Workspace layout (proven to fit: ~52.81 MB)
    const size_t offY   = 0;                                   // 12,800,000
    const size_t offEB  = (size_t)N_NODES * C * 4;             // +38,400,000
    const size_t offRS  = offEB + (size_t)NE * 8;              // 51,200,000
    const size_t offBS  = offRS + (((size_t)(NKEY + 1) * 4 + 255) & ~(size_t)255);
    const size_t offBC  = offBS + (((NBUCK + 1) * 4 + 255) & ~(size_t)255);
    const size_t offHC  = offBC + ((NBUCK * 4 + 255) & ~(size_t)255);
    const size_t need   = offHC + (size_t)NBUCK * 4;

    float* y = (float*)((char*)d_ws + offY);

    if (ws_size >= need) {
        int2* edgebuf  = (int2*)((char*)d_ws + offEB);
        int*  rs_start = (int*)((char*)d_ws + offRS);
        int*  bstart   = (int*)((char*)d_ws + offBS);
        int*  bcur     = (int*)((char*)d_ws + offBC);
        int*  hcnt     = (int*)((char*)d_ws + offHC);

        hipMemsetAsync(hcnt, 0, (size_t)NBUCK * 4, stream);
        hipMemsetAsync(out, 0, (size_t)N_NODES * C * sizeof(float), stream);

        gemm_hist_k<<<GEMM_BLOCKS + NHCHUNK, 256, 0, stream>>>(
            x, W, y, edge_rows, hcnt);
        scan_c<<<1, 256, 0, stream>>>(hcnt, bstart, bcur, rs_start);
        part1_k<<<NCHUNK1, 512, 0, stream>>>(edge_vals, edge_rows, edge_cols,
                                             alpha, bcur, edgebuf);
        part2_k<<<NBUCK, 512, 0, stream>>>(bstart, rs_start, edgebuf);
        gathers9_k<<<(N_NODES / 8) * NSLICE, 256, 0, stream>>>(
            (const long long*)edgebuf, rs_start, y, b, out);
    } else {
        gemm_only_k<<<GEMM_BLOCKS, 256, 0, stream>>>(x, W, y);
        hipMemsetAsync(out, 0, (size_t)N_NODES * C * sizeof(float), stream);
        const long long scatter_threads = (long long)KH * E * C;
        const int scatter_blocks = (int)((scatter_threads + 255) / 256);
        scatter_edges<<<scatter_blocks, 256, 0, stream>>>(
            edge_vals, edge_rows, edge_cols, alpha, y, out);
        finalize_k<<<(N_NODES * C / 4 + 255) / 256, 256, 0, stream>>>(out, b);
    }
}